// Round 1
// baseline (154.949 us; speedup 1.0000x reference)
//
#include <hip/hip_runtime.h>
#include <hip/hip_bf16.h>
#include <math.h>

#define N_CLS 16384
#define DDIM  128
#define LOG2E 1.4426950408889634f

#if __has_builtin(__builtin_amdgcn_exp2f)
#define EXP2(x) __builtin_amdgcn_exp2f(x)
#else
#define EXP2(x) exp2f(x)
#endif

typedef __attribute__((ext_vector_type(8))) short short8;   // 8 bf16 (4 VGPRs)
typedef __attribute__((ext_vector_type(16))) float f32x16;  // 32x32 MFMA accumulator

__device__ __forceinline__ unsigned short f2bf(float f) {
    __hip_bfloat16 h = __float2bfloat16(f);
    return *(unsigned short*)&h;
}

// ---------------------------------------------------------------------------
// 32x32x16 fragment layout (doubled-K analog of the verified 16x16x32 layout):
//   operand element (r, k) of a 32-row (or 32-col) tile, K=128 split in 8 kc:
//     lane = (k>>3 & 1)*32 + (r&31), j = k&7  (8 contiguous k per lane)
//     offset = tile*4096 + kc*512 + lane*8 + j      (shorts; tile = 8 KB)
// prep: block = one 32-row tile (512 blocks x 256 thr). Thread t covers
// kc = (t>>6)*2 + h (h=0,1), rows i = g*32 + (lane&31); writes are short8 at
// kc*512 + lane*8 -> per (wave,h) a contiguous 1 KB burst. ap via shfl+LDS.
// A rows = anchors * LOG2E (exp2 domain); B rows = negatives (x[2i+1]).
// NO CSHIFT: max |S|~70 -> exp2 inputs within +-102, safe in f32.
// ---------------------------------------------------------------------------
__global__ __launch_bounds__(256)
void prep_kernel(const float* __restrict__ x,
                 const int* __restrict__ aidx,
                 float* __restrict__ ap,
                 unsigned short* __restrict__ Afrag,
                 unsigned short* __restrict__ Bfrag,
                 float* __restrict__ out) {
    const int t = threadIdx.x;
    const int g = blockIdx.x;                 // 32-row tile index (512 blocks)
    const int lane = t & 63;
    const int w = t >> 6;                     // wave 0..3
    const int m = lane & 31;                  // row within tile
    const int half = lane >> 5;               // k sub-half (8 elems)
    const int i = g * 32 + m;                 // pair index
    const bool sel = (aidx[i] != 0);

    float d = 0.0f;
    #pragma unroll
    for (int h = 0; h < 2; ++h) {
        const int kc = w * 2 + h;
        const int k0 = kc * 16 + half * 8;
        float fa[8], fb[8];
        *(float4*)&fa[0] = *(const float4*)(x + (2L * i) * DDIM + k0);
        *(float4*)&fa[4] = *(const float4*)(x + (2L * i) * DDIM + k0 + 4);
        *(float4*)&fb[0] = *(const float4*)(x + (2L * i + 1) * DDIM + k0);
        *(float4*)&fb[4] = *(const float4*)(x + (2L * i + 1) * DDIM + k0 + 4);
        short8 As8, Bs8;
        #pragma unroll
        for (int j = 0; j < 8; ++j) {
            const float av = sel ? fb[j] : fa[j];
            As8[j] = (short)f2bf(av * LOG2E);
            Bs8[j] = (short)f2bf(fb[j]);
            d += fa[j] * fb[j];
        }
        *(short8*)(Afrag + (long)g * 4096 + kc * 512 + lane * 8) = As8;
        *(short8*)(Bfrag + (long)g * 4096 + kc * 512 + lane * 8) = Bs8;
    }
    // ap[i] = dot(x[2i], x[2i+1]) (symmetric in anchor/pos choice)
    d += __shfl_xor(d, 32, 64);               // combine the two k-halves
    __shared__ float sap[4][32];
    if (lane < 32) sap[w][lane] = d;
    __syncthreads();
    if (t < 32) ap[g * 32 + t] = sap[0][t] + sap[1][t] + sap[2][t] + sap[3][t];
    if (t == 0 && g == 0) out[0] = 0.0f;
}

// ---------------------------------------------------------------------------
// fused: 32x32x16 MFMA. block = (rt = bid>>3 : 128 output rows,
// oct = bid&7 : 2048-col octant, XCD-aligned so each octant's 512 KB B slice
// pins in one XCD L2). Wave w owns 32-row tile gRow = rt*4+w x full octant:
// 64 col-tiles, 8 chained MFMA each (K=128). B half-tile software pipeline
// (bP/bQ, 16 regs each, ~1 tile of prefetch distance). Per 32-col tile:
// 8 MFMA + 8 loads + 16 exp + 16 add  (~1.75 instr/col vs 3.4 before).
// Diagonal zeroed in the one (wave-uniform) tile where row range == col range.
// Register budget ~112 -> launch_bounds(256,4) holds 4 waves/SIMD.
// ---------------------------------------------------------------------------
__global__ __launch_bounds__(256, 4)
void fused_kernel(const unsigned short* __restrict__ Afrag,
                  const unsigned short* __restrict__ Bfrag,
                  float* __restrict__ partial) {
    const int tid = threadIdx.x;
    const int lane = tid & 63;
    const int w = tid >> 6;
    const int l31 = lane & 31;
    const int hi = lane >> 5;
    const int oct = blockIdx.x & 7;
    const int rt = blockIdx.x >> 3;
    const int gRow = rt * 4 + w;              // 32-row tile 0..511

    // hoist A: one 32-row tile, all 8 kc (32 VGPRs)
    short8 af[8];
    {
        const unsigned short* abase = Afrag + (long)gRow * 4096 + lane * 8;
        #pragma unroll
        for (int kc = 0; kc < 8; ++kc)
            af[kc] = *(const short8*)(abase + kc * 512);
    }
    const unsigned short* bbase = Bfrag + (long)oct * 64 * 4096 + lane * 8;

    // diagonal col-tile (wave-uniform): cols (oct*64+ct)*32 == rows gRow*32
    const int ctd0 = gRow - oct * 64;
    const int ctd = (ctd0 >= 0 && ctd0 < 64) ? ctd0 : -1;

    float rs[16];
    #pragma unroll
    for (int r = 0; r < 16; ++r) rs[r] = 0.0f;

    short8 bP[4], bQ[4];
    #pragma unroll
    for (int kc = 0; kc < 4; ++kc) bP[kc] = *(const short8*)(bbase + kc * 512);
    #pragma unroll
    for (int kc = 0; kc < 4; ++kc) bQ[kc] = *(const short8*)(bbase + 2048 + kc * 512);

    for (int ct = 0; ct < 64; ++ct) {
        // next tile (tile 63 harmlessly reloads itself; avoids a branch)
        const unsigned short* nb = bbase + (long)((ct < 63) ? ct + 1 : ct) * 4096;

        f32x16 acc;
        #pragma unroll
        for (int r = 0; r < 16; ++r) acc[r] = 0.0f;

        #pragma unroll
        for (int kc = 0; kc < 4; ++kc)
            acc = __builtin_amdgcn_mfma_f32_32x32x16_bf16(af[kc], bP[kc], acc, 0, 0, 0);
        #pragma unroll
        for (int kc = 0; kc < 4; ++kc)          // prefetch next first half
            bP[kc] = *(const short8*)(nb + kc * 512);
        #pragma unroll
        for (int kc = 0; kc < 4; ++kc)
            acc = __builtin_amdgcn_mfma_f32_32x32x16_bf16(af[4 + kc], bQ[kc], acc, 0, 0, 0);
        #pragma unroll
        for (int kc = 0; kc < 4; ++kc)          // prefetch next second half
            bQ[kc] = *(const short8*)(nb + 2048 + kc * 512);

        if (ct == ctd) {
            #pragma unroll
            for (int r = 0; r < 16; ++r) {
                const float e = EXP2(acc[r]);
                const int row = (r & 3) + 8 * (r >> 2) + 4 * hi;  // C/D row map
                rs[r] += (l31 == row) ? 0.0f : e;
            }
        } else {
            #pragma unroll
            for (int r = 0; r < 16; ++r) rs[r] += EXP2(acc[r]);
        }
    }

    // reduce across the 32 column lanes (per lane-half), one store per row
    #pragma unroll
    for (int r = 0; r < 16; ++r) {
        float v = rs[r];
        v += __shfl_xor(v, 1, 64);
        v += __shfl_xor(v, 2, 64);
        v += __shfl_xor(v, 4, 64);
        v += __shfl_xor(v, 8, 64);
        v += __shfl_xor(v, 16, 64);
        if (l31 == 0) {
            const int row = (r & 3) + 8 * (r >> 2) + 4 * hi;
            partial[(long)oct * N_CLS + (long)gRow * 32 + row] = v;
        }
    }
}

// ---------------------------------------------------------------------------
// finalize: per row s = sum of 8 octant partials (= sum_j exp(S_ij), j!=i);
// loss = log1p(s * exp(-ap)) via u = log(s) - ap; block-sum; atomicAdd.
// ---------------------------------------------------------------------------
__global__ __launch_bounds__(256)
void finalize_kernel(const float* __restrict__ partial,
                     const float* __restrict__ ap,
                     float* __restrict__ out) {
    __shared__ float red[256];
    const int t = threadIdx.x;
    const int row = blockIdx.x * 256 + t;
    float s = 0.0f;
    #pragma unroll
    for (int p = 0; p < 8; ++p) s += partial[(long)p * N_CLS + row];
    const float u = logf(s) - ap[row];
    const float loss = (u > 25.0f) ? u : log1pf(__expf(u));
    red[t] = loss;
    __syncthreads();
    for (int st = 128; st > 0; st >>= 1) {
        if (t < st) red[t] += red[t + st];
        __syncthreads();
    }
    if (t == 0) atomicAdd(out, red[0]);
}

extern "C" void kernel_launch(void* const* d_in, const int* in_sizes, int n_in,
                              void* d_out, int out_size, void* d_ws, size_t ws_size,
                              hipStream_t stream) {
    const float* x    = (const float*)d_in[0];
    const int*   aidx = (const int*)d_in[1];
    // d_in[2] (pos_idx) derivable; unused.

    char* ws = (char*)d_ws;
    float* ap             = (float*)(ws);                                   // 64 KB
    float* partial        = (float*)(ws + 131072);                          // 512 KB (8 slots)
    unsigned short* Afrag = (unsigned short*)(ws + 131072 + 1048576);       // 4 MB
    unsigned short* Bfrag = (unsigned short*)(ws + 131072 + 1048576 + 4194304); // 4 MB

    prep_kernel<<<N_CLS / 32, 256, 0, stream>>>(x, aidx, ap, Afrag, Bfrag, (float*)d_out);
    fused_kernel<<<1024, 256, 0, stream>>>(Afrag, Bfrag, partial);
    finalize_kernel<<<64, 256, 0, stream>>>(partial, ap, (float*)d_out);
}

// Round 2
// 141.105 us; speedup vs baseline: 1.0981x; 1.0981x over previous
//
#include <hip/hip_runtime.h>
#include <hip/hip_bf16.h>
#include <math.h>

#define N_CLS 16384
#define DDIM  128
#define LOG2E 1.4426950408889634f

#if __has_builtin(__builtin_amdgcn_exp2f)
#define EXP2(x) __builtin_amdgcn_exp2f(x)
#else
#define EXP2(x) exp2f(x)
#endif

typedef __attribute__((ext_vector_type(8))) short short8;   // 8 bf16 (4 VGPRs)
typedef __attribute__((ext_vector_type(16))) float f32x16;  // 32x32 MFMA accumulator

__device__ __forceinline__ unsigned short f2bf(float f) {
    __hip_bfloat16 h = __float2bfloat16(f);
    return *(unsigned short*)&h;
}

// ---------------------------------------------------------------------------
// 32x32x16 fragment layout (harness-verified in round 1):
//   element (rr, k) of a 32-row tile, K=128 in 8 kc chunks:
//     lane = (k>>3 & 1)*32 + (rr&31), j = k&7
//     short offset = tile*4096 + kc*512 + lane*8 + j     (tile = 8 KB)
//
// prep v3 (coalesced): block = 32 pairs (64 x-rows = 32 KB slab).
// Unit l = u*256 + t in [0,1024): row r = l>>4, k0 = (l&15)*8 -> 16
// consecutive threads read 512 B contiguous of one row (vs 1 KB-strided
// 16 B/lane before = 64 lines/instr). Even-row (anchor-candidate) threads
// also load the partner row (contiguous per 16-lane group): gives the
// anchor select AND the ap-dot locally; 4-step shfl reduce over the
// 16-lane row group. Odd-row threads write Bfrag. Frag writes keep the
// verified layout. No CSHIFT (|S|max ~70 -> exp2 args within +-102, f32-safe).
// ---------------------------------------------------------------------------
__global__ __launch_bounds__(256)
void prep_kernel(const float* __restrict__ x,
                 const int* __restrict__ aidx,
                 float* __restrict__ ap,
                 unsigned short* __restrict__ Afrag,
                 unsigned short* __restrict__ Bfrag,
                 float* __restrict__ out) {
    const int t = threadIdx.x;
    const int g = blockIdx.x;                  // 32 pairs per block (512 blocks)
    #pragma unroll
    for (int u = 0; u < 4; ++u) {
        const int l  = u * 256 + t;            // unit in [0,1024)
        const int r  = l >> 4;                 // slab row 0..63
        const int k0 = (l & 15) * 8;
        const float* src = x + (long)g * 8192 + (long)r * 128 + k0;
        float fa[8];
        *(float4*)&fa[0] = *(const float4*)(src);
        *(float4*)&fa[4] = *(const float4*)(src + 4);
        // frag dest for this unit: kc = (l&15)>>1, half = l&1, rr = r>>1
        const long dst = (long)g * 4096 +
                         ((l & 15) >> 1) * 512 + ((l & 1) * 32 + (r >> 1)) * 8;
        if (r & 1) {
            // negative row x[2i+1] -> Bfrag
            short8 B;
            #pragma unroll
            for (int j = 0; j < 8; ++j) B[j] = (short)f2bf(fa[j]);
            *(short8*)(Bfrag + dst) = B;
        } else {
            // even row: holds x[2i]; also load partner x[2i+1] (contiguous
            // per 16-lane group) for anchor select + ap dot
            float fb[8];
            *(float4*)&fb[0] = *(const float4*)(src + 128);
            *(float4*)&fb[4] = *(const float4*)(src + 132);
            const int i = g * 32 + (r >> 1);
            const bool sel = (aidx[i] != 0);
            short8 A;
            float d = 0.0f;
            #pragma unroll
            for (int j = 0; j < 8; ++j) {
                const float av = sel ? fb[j] : fa[j];
                A[j] = (short)f2bf(av * LOG2E);
                d += fa[j] * fb[j];
            }
            *(short8*)(Afrag + dst) = A;
            // reduce dot across the 16 lanes covering this row (all active)
            d += __shfl_xor(d, 1, 64);
            d += __shfl_xor(d, 2, 64);
            d += __shfl_xor(d, 4, 64);
            d += __shfl_xor(d, 8, 64);
            if ((t & 15) == 0) ap[i] = d;
        }
    }
    if (t == 0 && g == 0) out[0] = 0.0f;
}

// ---------------------------------------------------------------------------
// fused v3: LDS-shared B, 64 rows/wave.
// Round-1 diagnosis: every wave streamed its 512 KB B octant from L2 ->
// 2.1 GB L2 reads = 22.8 TB/s (66% of L2 ceiling) + single 8-deep MFMA
// chain/wave -> latency-bound at MfmaUtil 31%.
// Now: block = (rt: 256 rows) x (oct: 2048 cols, bid&7 XCD-aligned).
// B tile (8 KB) staged ONCE per block into double-buffered LDS (each wave
// reg-stages 2 chunks: load early, ds_write late). L2 B traffic /4 ->
// 536 MB (~15.5 us of L2 BW, under the 27.5 us MFMA floor). Wave owns TWO
// 32-row tiles (af0/af1): 2 independent MFMA chains (ILP) and halves
// LDS-read bytes per MFMA (0.5 KB/MFMA < pipe rate). One barrier/tile.
// launch_bounds(256,3): ~160 VGPR demand <= 168 cap, 3 blocks/CU, 48 KB LDS.
// ---------------------------------------------------------------------------
__global__ __launch_bounds__(256, 3)
void fused_kernel(const unsigned short* __restrict__ Afrag,
                  const unsigned short* __restrict__ Bfrag,
                  float* __restrict__ partial) {
    __shared__ __align__(16) unsigned short bs[2][4096];   // 2 x 8 KB
    const int tid  = threadIdx.x;
    const int lane = tid & 63;
    const int w    = tid >> 6;                 // wave 0..3
    const int l31  = lane & 31;
    const int hi   = lane >> 5;
    const int oct  = blockIdx.x & 7;           // XCD-aligned column octant
    const int rt   = blockIdx.x >> 3;          // 0..63 (256-row block)
    const int r0   = rt * 8 + w * 2;           // this wave's 32-row tiles
    const int r1   = r0 + 1;

    // hoist A: two 32-row tiles, all 8 kc (64 VGPRs)
    short8 af0[8], af1[8];
    {
        const unsigned short* a0 = Afrag + (long)r0 * 4096 + lane * 8;
        const unsigned short* a1 = Afrag + (long)r1 * 4096 + lane * 8;
        #pragma unroll
        for (int kc = 0; kc < 8; ++kc) {
            af0[kc] = *(const short8*)(a0 + kc * 512);
            af1[kc] = *(const short8*)(a1 + kc * 512);
        }
    }
    const unsigned short* bbase = Bfrag + (long)oct * (64L * 4096) + lane * 8;
    const int wchunk = w * 1024;               // this wave's 2 stage chunks

    // diagonal col-tiles (wave-uniform)
    const int ctd0 = r0 - oct * 64;
    const int ctd1 = r1 - oct * 64;

    float rs0[16], rs1[16];
    #pragma unroll
    for (int q = 0; q < 16; ++q) { rs0[q] = 0.0f; rs1[q] = 0.0f; }

    // prologue: stage tile 0 into bs[0]
    {
        short8 s0 = *(const short8*)(bbase + wchunk);
        short8 s1 = *(const short8*)(bbase + wchunk + 512);
        *(short8*)(&bs[0][wchunk + lane * 8]) = s0;
        *(short8*)(&bs[0][wchunk + 512 + lane * 8]) = s1;
    }
    __syncthreads();

    for (int ct = 0; ct < 64; ++ct) {
        const int cur = ct & 1;
        // issue next-tile loads early (HBM/L2 latency hides under MFMA+exp);
        // tile 63 harmlessly reloads itself (no reader of that ds_write)
        const long nt = (ct < 63) ? (long)(ct + 1) : 63L;
        short8 n0 = *(const short8*)(bbase + nt * 4096 + wchunk);
        short8 n1 = *(const short8*)(bbase + nt * 4096 + wchunk + 512);

        f32x16 acc0, acc1;
        #pragma unroll
        for (int q = 0; q < 16; ++q) { acc0[q] = 0.0f; acc1[q] = 0.0f; }

        const unsigned short* bp = &bs[cur][lane * 8];
        #pragma unroll
        for (int kc = 0; kc < 8; ++kc) {
            short8 b = *(const short8*)(bp + kc * 512);
            acc0 = __builtin_amdgcn_mfma_f32_32x32x16_bf16(af0[kc], b, acc0, 0, 0, 0);
            acc1 = __builtin_amdgcn_mfma_f32_32x32x16_bf16(af1[kc], b, acc1, 0, 0, 0);
        }

        if (ct == ctd0) {
            #pragma unroll
            for (int q = 0; q < 16; ++q) {
                const float e = EXP2(acc0[q]);
                const int row = (q & 3) + 8 * (q >> 2) + 4 * hi;  // C/D row map
                rs0[q] += (l31 == row) ? 0.0f : e;
            }
        } else {
            #pragma unroll
            for (int q = 0; q < 16; ++q) rs0[q] += EXP2(acc0[q]);
        }
        if (ct == ctd1) {
            #pragma unroll
            for (int q = 0; q < 16; ++q) {
                const float e = EXP2(acc1[q]);
                const int row = (q & 3) + 8 * (q >> 2) + 4 * hi;
                rs1[q] += (l31 == row) ? 0.0f : e;
            }
        } else {
            #pragma unroll
            for (int q = 0; q < 16; ++q) rs1[q] += EXP2(acc1[q]);
        }

        // write-late: staged tile -> other buffer (its readers finished at
        // the barrier ending iteration ct-1)
        *(short8*)(&bs[cur ^ 1][wchunk + lane * 8]) = n0;
        *(short8*)(&bs[cur ^ 1][wchunk + 512 + lane * 8]) = n1;
        __syncthreads();
    }

    // cross-column reduce (l31 bits via xor 1..16), one store per output row
    #pragma unroll
    for (int q = 0; q < 16; ++q) {
        float v0 = rs0[q], v1 = rs1[q];
        v0 += __shfl_xor(v0, 1, 64);  v1 += __shfl_xor(v1, 1, 64);
        v0 += __shfl_xor(v0, 2, 64);  v1 += __shfl_xor(v1, 2, 64);
        v0 += __shfl_xor(v0, 4, 64);  v1 += __shfl_xor(v1, 4, 64);
        v0 += __shfl_xor(v0, 8, 64);  v1 += __shfl_xor(v1, 8, 64);
        v0 += __shfl_xor(v0, 16, 64); v1 += __shfl_xor(v1, 16, 64);
        if (l31 == 0) {
            const int row = (q & 3) + 8 * (q >> 2) + 4 * hi;
            partial[(long)oct * N_CLS + (long)r0 * 32 + row] = v0;
            partial[(long)oct * N_CLS + (long)r1 * 32 + row] = v1;
        }
    }
}

// ---------------------------------------------------------------------------
// finalize: per row s = sum of 8 octant partials (= sum_j exp(S_ij), j!=i);
// loss = log1p(s * exp(-ap)) via u = log(s) - ap; block-sum; atomicAdd.
// ---------------------------------------------------------------------------
__global__ __launch_bounds__(256)
void finalize_kernel(const float* __restrict__ partial,
                     const float* __restrict__ ap,
                     float* __restrict__ out) {
    __shared__ float red[256];
    const int t = threadIdx.x;
    const int row = blockIdx.x * 256 + t;
    float s = 0.0f;
    #pragma unroll
    for (int p = 0; p < 8; ++p) s += partial[(long)p * N_CLS + row];
    const float u = logf(s) - ap[row];
    const float loss = (u > 25.0f) ? u : log1pf(__expf(u));
    red[t] = loss;
    __syncthreads();
    for (int st = 128; st > 0; st >>= 1) {
        if (t < st) red[t] += red[t + st];
        __syncthreads();
    }
    if (t == 0) atomicAdd(out, red[0]);
}

extern "C" void kernel_launch(void* const* d_in, const int* in_sizes, int n_in,
                              void* d_out, int out_size, void* d_ws, size_t ws_size,
                              hipStream_t stream) {
    const float* x    = (const float*)d_in[0];
    const int*   aidx = (const int*)d_in[1];
    // d_in[2] (pos_idx) derivable; unused.

    char* ws = (char*)d_ws;
    float* ap             = (float*)(ws);                                   // 64 KB
    float* partial        = (float*)(ws + 131072);                          // 512 KB (8 slots)
    unsigned short* Afrag = (unsigned short*)(ws + 131072 + 1048576);       // 4 MB
    unsigned short* Bfrag = (unsigned short*)(ws + 131072 + 1048576 + 4194304); // 4 MB

    prep_kernel<<<N_CLS / 32, 256, 0, stream>>>(x, aidx, ap, Afrag, Bfrag, (float*)d_out);
    fused_kernel<<<512, 256, 0, stream>>>(Afrag, Bfrag, partial);
    finalize_kernel<<<64, 256, 0, stream>>>(partial, ap, (float*)d_out);
}